// Round 1
// baseline (1769.120 us; speedup 1.0000x reference)
//
#include <hip/hip_runtime.h>

// Problem constants (baked into the reference)
#define NN 50000        // num nodes
#define EE 300000       // edges per type
#define HD 64           // hidden / feature size
#define CH_STRIDE (NN * HD)   // 3.2M floats per channel plane

// ---------------------------------------------------------------------------
// filt[b][l][c][t] = softmax(layerW_b[l][c][:])[t]   -> 2*2*2*3 = 24 floats
// ---------------------------------------------------------------------------
__global__ void filt_kernel(const float* __restrict__ lw0,
                            const float* __restrict__ lw1,
                            float* __restrict__ filt) {
    int i = threadIdx.x;           // use 0..7 : i = b*4 + l*2 + c
    if (i < 8) {
        int b = i >> 2, l = (i >> 1) & 1, c = i & 1;
        const float* lw = (b == 0 ? lw0 : lw1) + l * 6 + c * 3;
        float a0 = lw[0], a1 = lw[1], a2 = lw[2];
        float m  = fmaxf(a0, fmaxf(a1, a2));
        float e0 = expf(a0 - m), e1 = expf(a1 - m), e2 = expf(a2 - m);
        float s  = e0 + e1 + e2;
        float* o = filt + i * 3;
        o[0] = e0 / s; o[1] = e1 / s; o[2] = e2 / s;
    }
}

// ---------------------------------------------------------------------------
// H[c][n][o] = sum_f Xin[n][f] * Ws[c][f][o]      (F = O = 64, C = 2)
// block: 256 threads = 4 nodes x 64 outputs; Ws (both channels) staged in LDS
// ---------------------------------------------------------------------------
__global__ void __launch_bounds__(256)
proj_kernel(const float* __restrict__ Xin, const float* __restrict__ Ws,
            float* __restrict__ H) {
    __shared__ float Wl[2 * 64 * 64];   // 32 KB
    __shared__ float Xs[4][64];
    int tid = threadIdx.x;
    for (int i = tid; i < 2 * 64 * 64; i += 256) Wl[i] = Ws[i];
    int n0 = blockIdx.x * 4;
    {
        int ln = tid >> 6, f = tid & 63;
        Xs[ln][f] = Xin[(n0 + ln) * HD + f];
    }
    __syncthreads();
    int ln = tid >> 6, o = tid & 63;
    int n = n0 + ln;
    float a0 = 0.f, a1 = 0.f;
#pragma unroll
    for (int f = 0; f < 64; ++f) {
        float x = Xs[ln][f];
        a0 += x * Wl[f * 64 + o];
        a1 += x * Wl[4096 + f * 64 + o];
    }
    H[n * HD + o]             = a0;
    H[CH_STRIDE + n * HD + o] = a1;
}

// ---------------------------------------------------------------------------
// SpMM-mix, one edge type per blockIdx.y, one wave per edge, lane = feature.
// Hout[c][row] += filt[c][t] * val * Hin[c][col]   (atomic scatter)
// ---------------------------------------------------------------------------
__global__ void __launch_bounds__(256)
spmm_kernel(const float* __restrict__ Hin, float* __restrict__ Hout,
            const int* __restrict__ ei0, const int* __restrict__ ei1,
            const int* __restrict__ ei2,
            const float* __restrict__ ev0, const float* __restrict__ ev1,
            const float* __restrict__ ev2,
            const float* __restrict__ filt /* [2][3] for this (block,layer) */) {
    const int t = blockIdx.y;
    const int*   ei = (t == 0) ? ei0 : (t == 1) ? ei1 : ei2;
    const float* ev = (t == 0) ? ev0 : (t == 1) ? ev1 : ev2;
    const float f0 = filt[t];
    const float f1 = filt[3 + t];

    int e = blockIdx.x * 4 + (threadIdx.x >> 6);
    if (e >= EE) return;
    int f = threadIdx.x & 63;

    int   r = ei[e];        // destination (segment_sum index)
    int   c = ei[EE + e];   // source (gather index)
    float w = ev[e];

    float x0 = Hin[c * HD + f];
    float x1 = Hin[CH_STRIDE + c * HD + f];
    atomicAdd(&Hout[r * HD + f],             w * f0 * x0);
    atomicAdd(&Hout[CH_STRIDE + r * HD + f], w * f1 * x1);
}

// ---------------------------------------------------------------------------
// Epilogue: Hm = TP*relu(BETA*X0 + (1-BETA)*H) + (1-TP)*X0  (per [c][n][d])
//           out[n] = relu(concat_c(Hm[c][n]) @ linW + linb)   [128 -> 64]
// block: 256 threads = 4 nodes x 64 outputs; linW (32 KB) in LDS
// ---------------------------------------------------------------------------
__global__ void __launch_bounds__(256)
epilogue_kernel(const float* __restrict__ X0, const float* __restrict__ H,
                const float* __restrict__ linW, const float* __restrict__ linb,
                float* __restrict__ out) {
    __shared__ float Wl[128 * 64];   // 32 KB
    __shared__ float Hs[4][128];
    int tid = threadIdx.x;
    for (int i = tid; i < 128 * 64; i += 256) Wl[i] = linW[i];
    int n0 = blockIdx.x * 4;
    for (int i = tid; i < 4 * 128; i += 256) {
        int ln = i >> 7;
        int k  = i & 127;
        int c = k >> 6, d = k & 63;
        int n = n0 + ln;
        float x0 = X0[c * CH_STRIDE + n * HD + d];
        float h  = H [c * CH_STRIDE + n * HD + d];
        float z  = fmaxf(0.5f * x0 + 0.5f * h, 0.f);   // relu(BETA*X0+(1-B)*H)
        Hs[ln][k] = 0.8f * z + 0.2f * x0;              // TP mix
    }
    __syncthreads();
    int ln = tid >> 6, o = tid & 63;
    int n = n0 + ln;
    float acc = linb[o];
#pragma unroll
    for (int k = 0; k < 128; ++k)
        acc += Hs[ln][k] * Wl[k * 64 + o];
    out[n * HD + o] = fmaxf(acc, 0.f);
}

// ---------------------------------------------------------------------------
extern "C" void kernel_launch(void* const* d_in, const int* in_sizes, int n_in,
                              void* d_out, int out_size, void* d_ws, size_t ws_size,
                              hipStream_t stream) {
    const float* X     = (const float*)d_in[0];
    const float* ev0   = (const float*)d_in[1];
    const float* ev1   = (const float*)d_in[2];
    const float* ev2   = (const float*)d_in[3];
    const float* Ws0   = (const float*)d_in[4];
    const float* Ws1   = (const float*)d_in[5];
    const float* lw0   = (const float*)d_in[6];
    const float* lw1   = (const float*)d_in[7];
    const float* linW0 = (const float*)d_in[8];
    const float* linb0 = (const float*)d_in[9];
    const float* linW1 = (const float*)d_in[10];
    const float* linb1 = (const float*)d_in[11];
    const int*   ei0   = (const int*)d_in[12];
    const int*   ei1   = (const int*)d_in[13];
    const int*   ei2   = (const int*)d_in[14];
    float* out = (float*)d_out;

    // Workspace layout (floats): X0 | Ha | Hb | filt   (3*6.4M + 24)
    float* ws   = (float*)d_ws;
    float* X0   = ws;
    float* Ha   = ws + 2 * CH_STRIDE;
    float* Hb   = ws + 4 * CH_STRIDE;
    float* filt = ws + 6 * CH_STRIDE;
    const size_t Hbytes = (size_t)2 * CH_STRIDE * sizeof(float);

    filt_kernel<<<1, 64, 0, stream>>>(lw0, lw1, filt);

    dim3 spmm_grid(EE / 4, 3);

    // ---- FastGTN block 0 ----
    proj_kernel<<<NN / 4, 256, 0, stream>>>(X, Ws0, X0);
    hipMemsetAsync(Ha, 0, Hbytes, stream);
    spmm_kernel<<<spmm_grid, 256, 0, stream>>>(X0, Ha, ei0, ei1, ei2,
                                               ev0, ev1, ev2, filt + 0);
    hipMemsetAsync(Hb, 0, Hbytes, stream);
    spmm_kernel<<<spmm_grid, 256, 0, stream>>>(Ha, Hb, ei0, ei1, ei2,
                                               ev0, ev1, ev2, filt + 6);
    // epilogue writes block-0 output [N,64] into (dead) Ha
    epilogue_kernel<<<NN / 4, 256, 0, stream>>>(X0, Hb, linW0, linb0, Ha);

    // ---- FastGTN block 1 ----
    proj_kernel<<<NN / 4, 256, 0, stream>>>(Ha, Ws1, X0);
    hipMemsetAsync(Hb, 0, Hbytes, stream);
    spmm_kernel<<<spmm_grid, 256, 0, stream>>>(X0, Hb, ei0, ei1, ei2,
                                               ev0, ev1, ev2, filt + 12);
    hipMemsetAsync(Ha, 0, Hbytes, stream);
    spmm_kernel<<<spmm_grid, 256, 0, stream>>>(Hb, Ha, ei0, ei1, ei2,
                                               ev0, ev1, ev2, filt + 18);
    epilogue_kernel<<<NN / 4, 256, 0, stream>>>(X0, Ha, linW1, linb1, out);
}

// Round 2
// 733.414 us; speedup vs baseline: 2.4122x; 2.4122x over previous
//
#include <hip/hip_runtime.h>

// Problem constants
#define NN 50000              // num nodes
#define EE 300000             // edges per type
#define ETOT (3 * EE)         // 900000
#define HD 64                 // hidden / feature size
#define CH_STRIDE (NN * HD)   // floats per channel plane

// H layout throughout: float2 H2[N][64], H2[n][f] = (channel0_f, channel1_f)

// ---------------------------------------------------------------------------
// filt[b][l][c][t] = softmax(layerW_b[l][c][:])[t]   -> 2*2*2*3 = 24 floats
// ---------------------------------------------------------------------------
__global__ void filt_kernel(const float* __restrict__ lw0,
                            const float* __restrict__ lw1,
                            float* __restrict__ filt) {
    int i = threadIdx.x;
    if (i < 8) {
        int b = i >> 2, l = (i >> 1) & 1, c = i & 1;
        const float* lw = (b == 0 ? lw0 : lw1) + l * 6 + c * 3;
        float a0 = lw[0], a1 = lw[1], a2 = lw[2];
        float m  = fmaxf(a0, fmaxf(a1, a2));
        float e0 = expf(a0 - m), e1 = expf(a1 - m), e2 = expf(a2 - m);
        float s  = e0 + e1 + e2;
        float* o = filt + i * 3;
        o[0] = e0 / s; o[1] = e1 / s; o[2] = e2 / s;
    }
}

// ---------------------------------------------------------------------------
// CSR build: histogram -> exclusive scan -> scatter (once per launch; the
// graph is identical for all 4 spmm passes)
// ---------------------------------------------------------------------------
__global__ void __launch_bounds__(256)
hist_kernel(const int* __restrict__ ei0, const int* __restrict__ ei1,
            const int* __restrict__ ei2, int* __restrict__ cnt) {
    int t = blockIdx.y;
    const int* ei = (t == 0) ? ei0 : (t == 1) ? ei1 : ei2;
    int e = blockIdx.x * 256 + threadIdx.x;
    if (e < EE) atomicAdd(&cnt[ei[e]], 1);
}

// single-block scan over NN counts -> rp[NN+1] (exclusive) and cursor copy
__global__ void __launch_bounds__(1024)
scan_kernel(const int* __restrict__ cnt, int* __restrict__ rp,
            int* __restrict__ cursor) {
    __shared__ int s[1024];
    __shared__ int base_s;
    int tid = threadIdx.x;
    if (tid == 0) { base_s = 0; rp[0] = 0; }
    __syncthreads();
    for (int chunk = 0; chunk < NN; chunk += 1024) {
        int i = chunk + tid;
        int v = (i < NN) ? cnt[i] : 0;
        s[tid] = v;
        __syncthreads();
        for (int d = 1; d < 1024; d <<= 1) {
            int t = (tid >= d) ? s[tid - d] : 0;
            __syncthreads();
            s[tid] += t;
            __syncthreads();
        }
        int incl = s[tid];
        int base = base_s;          // read before base_s is updated below
        if (i < NN) {
            rp[i + 1]  = base + incl;
            cursor[i]  = base + incl - v;
        }
        __syncthreads();
        if (tid == 1023) base_s = base + incl;
        __syncthreads();
    }
}

// meta[pos] = { col | (etype<<16), bits(val) }  -- col < 65536 guaranteed
__global__ void __launch_bounds__(256)
scatter_kernel(const int* __restrict__ ei0, const int* __restrict__ ei1,
               const int* __restrict__ ei2,
               const float* __restrict__ ev0, const float* __restrict__ ev1,
               const float* __restrict__ ev2,
               int* __restrict__ cursor, int2* __restrict__ meta) {
    int t = blockIdx.y;
    const int*   ei = (t == 0) ? ei0 : (t == 1) ? ei1 : ei2;
    const float* ev = (t == 0) ? ev0 : (t == 1) ? ev1 : ev2;
    int e = blockIdx.x * 256 + threadIdx.x;
    if (e >= EE) return;
    int row = ei[e];
    int col = ei[EE + e];
    int pos = atomicAdd(&cursor[row], 1);
    meta[pos] = make_int2(col | (t << 16), __float_as_int(ev[e]));
}

// ---------------------------------------------------------------------------
// Projection: H2[n][o] = ( X@Ws[0], X@Ws[1] )[n][o]
// ---------------------------------------------------------------------------
__global__ void __launch_bounds__(256)
proj_kernel(const float* __restrict__ Xin, const float* __restrict__ Ws,
            float2* __restrict__ H2) {
    __shared__ float Wl[2 * 64 * 64];
    __shared__ float Xs[4][64];
    int tid = threadIdx.x;
    for (int i = tid; i < 2 * 64 * 64; i += 256) Wl[i] = Ws[i];
    int n0 = blockIdx.x * 4;
    {
        int ln = tid >> 6, f = tid & 63;
        Xs[ln][f] = Xin[(n0 + ln) * HD + f];
    }
    __syncthreads();
    int ln = tid >> 6, o = tid & 63;
    int n = n0 + ln;
    float a0 = 0.f, a1 = 0.f;
#pragma unroll
    for (int f = 0; f < 64; ++f) {
        float x = Xs[ln][f];
        a0 += x * Wl[f * 64 + o];
        a1 += x * Wl[4096 + f * 64 + o];
    }
    H2[n * HD + o] = make_float2(a0, a1);
}

// ---------------------------------------------------------------------------
// CSR SpMM-mix: one wave per destination row, lane = feature.
// acc_c = sum_edges val*filt[c][etype] * Hin2[col][lane].c ; one store per row
// ---------------------------------------------------------------------------
__global__ void __launch_bounds__(256)
spmm_kernel(const float2* __restrict__ Hin, float2* __restrict__ Hout,
            const int2* __restrict__ meta, const int* __restrict__ rp,
            const float* __restrict__ filt /* [2][3] for this (block,layer) */) {
    int wid  = threadIdx.x >> 6;
    int lane = threadIdx.x & 63;
    int row  = blockIdx.x * 4 + wid;

    float f00 = filt[0], f01 = filt[1], f02 = filt[2];
    float f10 = filt[3], f11 = filt[4], f12 = filt[5];

    int beg = rp[row], end = rp[row + 1];
    float acc0 = 0.f, acc1 = 0.f;

    for (int j0 = beg; j0 < end; j0 += 64) {
        int2 m = (j0 + lane < end) ? meta[j0 + lane] : make_int2(0, 0);
        int cnt = min(end - j0, 64);
        for (int k = 0; k < cnt; ++k) {
            int   mm = __shfl(m.x, k);
            float v  = __int_as_float(__shfl(m.y, k));
            int col = mm & 0xffff;
            int et  = mm >> 16;
            float2 x = Hin[col * HD + lane];
            float w0 = v * ((et == 0) ? f00 : (et == 1) ? f01 : f02);
            float w1 = v * ((et == 0) ? f10 : (et == 1) ? f11 : f12);
            acc0 += w0 * x.x;
            acc1 += w1 * x.y;
        }
    }
    Hout[row * HD + lane] = make_float2(acc0, acc1);
}

// ---------------------------------------------------------------------------
// Epilogue: Hm = TP*relu(BETA*X0+(1-BETA)*H) + (1-TP)*X0, then [128->64] + relu
// ---------------------------------------------------------------------------
__global__ void __launch_bounds__(256)
epilogue_kernel(const float2* __restrict__ X0, const float2* __restrict__ H,
                const float* __restrict__ linW, const float* __restrict__ linb,
                float* __restrict__ out) {
    __shared__ float Wl[128 * 64];
    __shared__ float Hs[4][128];
    int tid = threadIdx.x;
    for (int i = tid; i < 128 * 64; i += 256) Wl[i] = linW[i];
    int n0 = blockIdx.x * 4;
    {
        int ln = tid >> 6, d = tid & 63;
        int n = n0 + ln;
        float2 x0 = X0[n * HD + d];
        float2 h  = H [n * HD + d];
        float z0 = fmaxf(0.5f * x0.x + 0.5f * h.x, 0.f);
        float z1 = fmaxf(0.5f * x0.y + 0.5f * h.y, 0.f);
        Hs[ln][d]      = 0.8f * z0 + 0.2f * x0.x;
        Hs[ln][64 + d] = 0.8f * z1 + 0.2f * x0.y;
    }
    __syncthreads();
    int ln = tid >> 6, o = tid & 63;
    int n = n0 + ln;
    float acc = linb[o];
#pragma unroll
    for (int k = 0; k < 128; ++k)
        acc += Hs[ln][k] * Wl[k * 64 + o];
    out[n * HD + o] = fmaxf(acc, 0.f);
}

// ---------------------------------------------------------------------------
extern "C" void kernel_launch(void* const* d_in, const int* in_sizes, int n_in,
                              void* d_out, int out_size, void* d_ws, size_t ws_size,
                              hipStream_t stream) {
    const float* X     = (const float*)d_in[0];
    const float* ev0   = (const float*)d_in[1];
    const float* ev1   = (const float*)d_in[2];
    const float* ev2   = (const float*)d_in[3];
    const float* Ws0   = (const float*)d_in[4];
    const float* Ws1   = (const float*)d_in[5];
    const float* lw0   = (const float*)d_in[6];
    const float* lw1   = (const float*)d_in[7];
    const float* linW0 = (const float*)d_in[8];
    const float* linb0 = (const float*)d_in[9];
    const float* linW1 = (const float*)d_in[10];
    const float* linb1 = (const float*)d_in[11];
    const int*   ei0   = (const int*)d_in[12];
    const int*   ei1   = (const int*)d_in[13];
    const int*   ei2   = (const int*)d_in[14];
    float* out = (float*)d_out;

    // Workspace layout (4-byte units):
    // X0 | Ha | Hb  (each 2*CH_STRIDE)  | filt(24) | cnt(NN) | rp(NN+1) |
    // cursor(NN) | meta(2*ETOT)
    float* ws     = (float*)d_ws;
    float2* X0    = (float2*)(ws);
    float2* Ha    = (float2*)(ws + 2 * CH_STRIDE);
    float2* Hb    = (float2*)(ws + 4 * CH_STRIDE);
    float* filt   = ws + 6 * CH_STRIDE;
    int*   cnt    = (int*)(filt + 24);
    int*   rp     = cnt + NN;
    int*   cursor = rp + NN + 1;
    int2*  meta   = (int2*)(cursor + NN);

    // ---- build filters + CSR (once; shared by all 4 spmm passes) ----
    filt_kernel<<<1, 64, 0, stream>>>(lw0, lw1, filt);
    hipMemsetAsync(cnt, 0, NN * sizeof(int), stream);
    dim3 egrid((EE + 255) / 256, 3);
    hist_kernel<<<egrid, 256, 0, stream>>>(ei0, ei1, ei2, cnt);
    scan_kernel<<<1, 1024, 0, stream>>>(cnt, rp, cursor);
    scatter_kernel<<<egrid, 256, 0, stream>>>(ei0, ei1, ei2, ev0, ev1, ev2,
                                              cursor, meta);

    // ---- FastGTN block 0 ----
    proj_kernel<<<NN / 4, 256, 0, stream>>>(X, Ws0, X0);
    spmm_kernel<<<NN / 4, 256, 0, stream>>>(X0, Ha, meta, rp, filt + 0);
    spmm_kernel<<<NN / 4, 256, 0, stream>>>(Ha, Hb, meta, rp, filt + 6);
    // epilogue writes block-0 output [N,64] floats into (dead) Ha
    epilogue_kernel<<<NN / 4, 256, 0, stream>>>(X0, Hb, linW0, linb0, (float*)Ha);

    // ---- FastGTN block 1 ----
    proj_kernel<<<NN / 4, 256, 0, stream>>>((const float*)Ha, Ws1, X0);
    spmm_kernel<<<NN / 4, 256, 0, stream>>>(X0, Hb, meta, rp, filt + 12);
    spmm_kernel<<<NN / 4, 256, 0, stream>>>(Hb, Ha, meta, rp, filt + 18);
    epilogue_kernel<<<NN / 4, 256, 0, stream>>>(X0, Ha, linW1, linb1, out);
}

// Round 3
// 617.274 us; speedup vs baseline: 2.8660x; 1.1882x over previous
//
#include <hip/hip_runtime.h>

// Problem constants
#define NN 50000              // num nodes
#define EE 300000             // edges per type
#define ETOT (3 * EE)         // 900000
#define HD 64                 // hidden / feature size
#define CH_STRIDE (NN * HD)   // floats per channel plane
#define SCAN_BLOCKS ((NN + 1023) / 1024)   // 49

// H layout throughout: float2 H2[N][64], H2[n][f] = (channel0_f, channel1_f)

// ---------------------------------------------------------------------------
// filt[b][l][c][t] = softmax(layerW_b[l][c][:])[t]   -> 2*2*2*3 = 24 floats
// ---------------------------------------------------------------------------
__global__ void filt_kernel(const float* __restrict__ lw0,
                            const float* __restrict__ lw1,
                            float* __restrict__ filt) {
    int i = threadIdx.x;
    if (i < 8) {
        int b = i >> 2, l = (i >> 1) & 1, c = i & 1;
        const float* lw = (b == 0 ? lw0 : lw1) + l * 6 + c * 3;
        float a0 = lw[0], a1 = lw[1], a2 = lw[2];
        float m  = fmaxf(a0, fmaxf(a1, a2));
        float e0 = expf(a0 - m), e1 = expf(a1 - m), e2 = expf(a2 - m);
        float s  = e0 + e1 + e2;
        float* o = filt + i * 3;
        o[0] = e0 / s; o[1] = e1 / s; o[2] = e2 / s;
    }
}

// ---------------------------------------------------------------------------
// CSR build: histogram -> 3-phase multi-block exclusive scan -> scatter
// ---------------------------------------------------------------------------
__global__ void __launch_bounds__(256)
hist_kernel(const int* __restrict__ ei0, const int* __restrict__ ei1,
            const int* __restrict__ ei2, int* __restrict__ cnt) {
    int t = blockIdx.y;
    const int* ei = (t == 0) ? ei0 : (t == 1) ? ei1 : ei2;
    int e = blockIdx.x * 256 + threadIdx.x;
    if (e < EE) atomicAdd(&cnt[ei[e]], 1);
}

// Phase A: per-block inclusive scan (wave shuffles), write block sums
__global__ void __launch_bounds__(1024)
scanA_kernel(const int* __restrict__ cnt, int* __restrict__ incl,
             int* __restrict__ bsum) {
    __shared__ int wsum[16];
    int tid = threadIdx.x;
    int i = blockIdx.x * 1024 + tid;
    int lane = tid & 63, wv = tid >> 6;
    int v = (i < NN) ? cnt[i] : 0;
    int x = v;
#pragma unroll
    for (int d = 1; d < 64; d <<= 1) {
        int y = __shfl_up(x, d);
        if (lane >= d) x += y;
    }
    if (lane == 63) wsum[wv] = x;
    __syncthreads();
    if (wv == 0 && lane < 16) {
        int y = wsum[lane];
#pragma unroll
        for (int d = 1; d < 16; d <<= 1) {
            int z = __shfl_up(y, d);
            if (lane >= d) y += z;
        }
        wsum[lane] = y;
    }
    __syncthreads();
    if (wv > 0) x += wsum[wv - 1];
    if (i < NN) incl[i] = x;
    if (tid == 1023) bsum[blockIdx.x] = x;
}

// Phase B: exclusive scan of the 49 block sums (single wave)
__global__ void __launch_bounds__(64)
scanB_kernel(int* __restrict__ bsum) {
    int lane = threadIdx.x;
    int v = (lane < SCAN_BLOCKS) ? bsum[lane] : 0;
    int x = v;
#pragma unroll
    for (int d = 1; d < 64; d <<= 1) {
        int y = __shfl_up(x, d);
        if (lane >= d) x += y;
    }
    if (lane < SCAN_BLOCKS) bsum[lane] = x - v;   // exclusive
}

// Phase C: rp[i+1] = incl[i] + bsum[block]; cursor[i] = rp[i+1] - cnt[i]
__global__ void __launch_bounds__(1024)
scanC_kernel(const int* __restrict__ cnt, const int* __restrict__ incl,
             const int* __restrict__ bsum, int* __restrict__ rp,
             int* __restrict__ cursor) {
    int i = blockIdx.x * 1024 + threadIdx.x;
    if (i < NN) {
        int total = incl[i] + bsum[blockIdx.x];
        rp[i + 1] = total;
        cursor[i] = total - cnt[i];
    }
    if (i == 0) rp[0] = 0;
}

// meta[pos] = { col | (etype<<16), bits(val) }  -- col < 65536 guaranteed
__global__ void __launch_bounds__(256)
scatter_kernel(const int* __restrict__ ei0, const int* __restrict__ ei1,
               const int* __restrict__ ei2,
               const float* __restrict__ ev0, const float* __restrict__ ev1,
               const float* __restrict__ ev2,
               int* __restrict__ cursor, int2* __restrict__ meta) {
    int t = blockIdx.y;
    const int*   ei = (t == 0) ? ei0 : (t == 1) ? ei1 : ei2;
    const float* ev = (t == 0) ? ev0 : (t == 1) ? ev1 : ev2;
    int e = blockIdx.x * 256 + threadIdx.x;
    if (e >= EE) return;
    int row = ei[e];
    int col = ei[EE + e];
    int pos = atomicAdd(&cursor[row], 1);
    meta[pos] = make_int2(col | (t << 16), __float_as_int(ev[e]));
}

// ---------------------------------------------------------------------------
// Projection: H2[n][o] = ( X@Ws[0], X@Ws[1] )[n][o]
// ---------------------------------------------------------------------------
__global__ void __launch_bounds__(256)
proj_kernel(const float* __restrict__ Xin, const float* __restrict__ Ws,
            float2* __restrict__ H2) {
    __shared__ float Wl[2 * 64 * 64];
    __shared__ float Xs[4][64];
    int tid = threadIdx.x;
    for (int i = tid; i < 2 * 64 * 64; i += 256) Wl[i] = Ws[i];
    int n0 = blockIdx.x * 4;
    {
        int ln = tid >> 6, f = tid & 63;
        Xs[ln][f] = Xin[(n0 + ln) * HD + f];
    }
    __syncthreads();
    int ln = tid >> 6, o = tid & 63;
    int n = n0 + ln;
    float a0 = 0.f, a1 = 0.f;
#pragma unroll
    for (int f = 0; f < 64; ++f) {
        float x = Xs[ln][f];
        a0 += x * Wl[f * 64 + o];
        a1 += x * Wl[4096 + f * 64 + o];
    }
    H2[n * HD + o] = make_float2(a0, a1);
}

// ---------------------------------------------------------------------------
// CSR SpMM-mix: one wave per destination row, lane = feature, 4-edge unroll.
// ---------------------------------------------------------------------------
__global__ void __launch_bounds__(256)
spmm_kernel(const float2* __restrict__ Hin, float2* __restrict__ Hout,
            const int2* __restrict__ meta, const int* __restrict__ rp,
            const float* __restrict__ filt /* [2][3] for this (block,layer) */) {
    int wid  = threadIdx.x >> 6;
    int lane = threadIdx.x & 63;
    int row  = blockIdx.x * 4 + wid;

    const float f00 = filt[0], f01 = filt[1], f02 = filt[2];
    const float f10 = filt[3], f11 = filt[4], f12 = filt[5];

    int beg = rp[row], end = rp[row + 1];
    float acc0 = 0.f, acc1 = 0.f;

    for (int j0 = beg; j0 < end; j0 += 64) {
        int cnt = min(end - j0, 64);
        int2 m = (lane < cnt) ? meta[j0 + lane] : make_int2(0, 0);
        int k = 0;
        for (; k + 4 <= cnt; k += 4) {
            int mm0 = __shfl(m.x, k);
            int mm1 = __shfl(m.x, k + 1);
            int mm2 = __shfl(m.x, k + 2);
            int mm3 = __shfl(m.x, k + 3);
            float v0 = __int_as_float(__shfl(m.y, k));
            float v1 = __int_as_float(__shfl(m.y, k + 1));
            float v2 = __int_as_float(__shfl(m.y, k + 2));
            float v3 = __int_as_float(__shfl(m.y, k + 3));
            float2 x0 = Hin[(mm0 & 0xffff) * HD + lane];
            float2 x1 = Hin[(mm1 & 0xffff) * HD + lane];
            float2 x2 = Hin[(mm2 & 0xffff) * HD + lane];
            float2 x3 = Hin[(mm3 & 0xffff) * HD + lane];
            int e0 = mm0 >> 16, e1 = mm1 >> 16, e2 = mm2 >> 16, e3 = mm3 >> 16;
            acc0 += v0 * ((e0 == 0) ? f00 : (e0 == 1) ? f01 : f02) * x0.x;
            acc1 += v0 * ((e0 == 0) ? f10 : (e0 == 1) ? f11 : f12) * x0.y;
            acc0 += v1 * ((e1 == 0) ? f00 : (e1 == 1) ? f01 : f02) * x1.x;
            acc1 += v1 * ((e1 == 0) ? f10 : (e1 == 1) ? f11 : f12) * x1.y;
            acc0 += v2 * ((e2 == 0) ? f00 : (e2 == 1) ? f01 : f02) * x2.x;
            acc1 += v2 * ((e2 == 0) ? f10 : (e2 == 1) ? f11 : f12) * x2.y;
            acc0 += v3 * ((e3 == 0) ? f00 : (e3 == 1) ? f01 : f02) * x3.x;
            acc1 += v3 * ((e3 == 0) ? f10 : (e3 == 1) ? f11 : f12) * x3.y;
        }
        for (; k < cnt; ++k) {
            int mm = __shfl(m.x, k);
            float v = __int_as_float(__shfl(m.y, k));
            float2 x = Hin[(mm & 0xffff) * HD + lane];
            int et = mm >> 16;
            acc0 += v * ((et == 0) ? f00 : (et == 1) ? f01 : f02) * x.x;
            acc1 += v * ((et == 0) ? f10 : (et == 1) ? f11 : f12) * x.y;
        }
    }
    Hout[row * HD + lane] = make_float2(acc0, acc1);
}

// ---------------------------------------------------------------------------
// Epilogue: Hm = TP*relu(BETA*X0+(1-BETA)*H) + (1-TP)*X0, then [128->64] + relu
// ---------------------------------------------------------------------------
__global__ void __launch_bounds__(256)
epilogue_kernel(const float2* __restrict__ X0, const float2* __restrict__ H,
                const float* __restrict__ linW, const float* __restrict__ linb,
                float* __restrict__ out) {
    __shared__ float Wl[128 * 64];
    __shared__ float Hs[4][128];
    int tid = threadIdx.x;
    for (int i = tid; i < 128 * 64; i += 256) Wl[i] = linW[i];
    int n0 = blockIdx.x * 4;
    {
        int ln = tid >> 6, d = tid & 63;
        int n = n0 + ln;
        float2 x0 = X0[n * HD + d];
        float2 h  = H [n * HD + d];
        float z0 = fmaxf(0.5f * x0.x + 0.5f * h.x, 0.f);
        float z1 = fmaxf(0.5f * x0.y + 0.5f * h.y, 0.f);
        Hs[ln][d]      = 0.8f * z0 + 0.2f * x0.x;
        Hs[ln][64 + d] = 0.8f * z1 + 0.2f * x0.y;
    }
    __syncthreads();
    int ln = tid >> 6, o = tid & 63;
    int n = n0 + ln;
    float acc = linb[o];
#pragma unroll
    for (int k = 0; k < 128; ++k)
        acc += Hs[ln][k] * Wl[k * 64 + o];
    out[n * HD + o] = fmaxf(acc, 0.f);
}

// ---------------------------------------------------------------------------
extern "C" void kernel_launch(void* const* d_in, const int* in_sizes, int n_in,
                              void* d_out, int out_size, void* d_ws, size_t ws_size,
                              hipStream_t stream) {
    const float* X     = (const float*)d_in[0];
    const float* ev0   = (const float*)d_in[1];
    const float* ev1   = (const float*)d_in[2];
    const float* ev2   = (const float*)d_in[3];
    const float* Ws0   = (const float*)d_in[4];
    const float* Ws1   = (const float*)d_in[5];
    const float* lw0   = (const float*)d_in[6];
    const float* lw1   = (const float*)d_in[7];
    const float* linW0 = (const float*)d_in[8];
    const float* linb0 = (const float*)d_in[9];
    const float* linW1 = (const float*)d_in[10];
    const float* linb1 = (const float*)d_in[11];
    const int*   ei0   = (const int*)d_in[12];
    const int*   ei1   = (const int*)d_in[13];
    const int*   ei2   = (const int*)d_in[14];
    float* out = (float*)d_out;

    // Workspace layout (4-byte units):
    // X0 | Ha | Hb (each 2*CH_STRIDE) | filt(24) | cnt(NN) | incl(NN) |
    // bsum(64) | rp(NN+1) | cursor(NN) | meta(2*ETOT)
    float* ws     = (float*)d_ws;
    float2* X0    = (float2*)(ws);
    float2* Ha    = (float2*)(ws + 2 * CH_STRIDE);
    float2* Hb    = (float2*)(ws + 4 * CH_STRIDE);
    float* filt   = ws + 6 * CH_STRIDE;
    int*   cnt    = (int*)(filt + 24);
    int*   incl   = cnt + NN;
    int*   bsum   = incl + NN;
    int*   rp     = bsum + 64;
    int*   cursor = rp + NN + 1;
    int2*  meta   = (int2*)(cursor + NN);

    // ---- build filters + CSR (once; shared by all 4 spmm passes) ----
    filt_kernel<<<1, 64, 0, stream>>>(lw0, lw1, filt);
    hipMemsetAsync(cnt, 0, NN * sizeof(int), stream);
    dim3 egrid((EE + 255) / 256, 3);
    hist_kernel<<<egrid, 256, 0, stream>>>(ei0, ei1, ei2, cnt);
    scanA_kernel<<<SCAN_BLOCKS, 1024, 0, stream>>>(cnt, incl, bsum);
    scanB_kernel<<<1, 64, 0, stream>>>(bsum);
    scanC_kernel<<<SCAN_BLOCKS, 1024, 0, stream>>>(cnt, incl, bsum, rp, cursor);
    scatter_kernel<<<egrid, 256, 0, stream>>>(ei0, ei1, ei2, ev0, ev1, ev2,
                                              cursor, meta);

    // ---- FastGTN block 0 ----
    proj_kernel<<<NN / 4, 256, 0, stream>>>(X, Ws0, X0);
    spmm_kernel<<<NN / 4, 256, 0, stream>>>(X0, Ha, meta, rp, filt + 0);
    spmm_kernel<<<NN / 4, 256, 0, stream>>>(Ha, Hb, meta, rp, filt + 6);
    // epilogue writes block-0 output [N,64] floats into (dead) Ha
    epilogue_kernel<<<NN / 4, 256, 0, stream>>>(X0, Hb, linW0, linb0, (float*)Ha);

    // ---- FastGTN block 1 ----
    proj_kernel<<<NN / 4, 256, 0, stream>>>((const float*)Ha, Ws1, X0);
    spmm_kernel<<<NN / 4, 256, 0, stream>>>(X0, Hb, meta, rp, filt + 12);
    spmm_kernel<<<NN / 4, 256, 0, stream>>>(Hb, Ha, meta, rp, filt + 18);
    epilogue_kernel<<<NN / 4, 256, 0, stream>>>(X0, Ha, linW1, linb1, out);
}